// Round 2
// baseline (743.667 us; speedup 1.0000x reference)
//
#include <hip/hip_runtime.h>
#include <math.h>

namespace {

constexpr int SEQ   = 16;
constexpr int CDIM  = 256;
constexpr int NLAT  = 8;
constexpr int NR    = 48;    // 3*SEQ state rows (l,a,v)
constexpr int STRIDE = 260;  // padded LDS row stride in floats

// Multi-value packing butterfly: acc[8] over a 16-lane group (id = lane&15).
// Returns the group-wide sum of acc[id&7] on every lane.
__device__ __forceinline__ float reduce8x16(const float acc[8], int id) {
    float p4[4];
    #pragma unroll
    for (int q = 0; q < 4; ++q) {
        const float a = acc[2*q]   + __shfl_xor(acc[2*q],   1);
        const float b = acc[2*q+1] + __shfl_xor(acc[2*q+1], 1);
        p4[q] = (id & 1) ? b : a;
    }
    float p2[2];
    #pragma unroll
    for (int q = 0; q < 2; ++q) {
        const float a = p4[2*q]   + __shfl_xor(p4[2*q],   2);
        const float b = p4[2*q+1] + __shfl_xor(p4[2*q+1], 2);
        p2[q] = (id & 2) ? b : a;
    }
    const float a = p2[0] + __shfl_xor(p2[0], 4);
    const float b = p2[1] + __shfl_xor(p2[1], 4);
    float r = (id & 4) ? b : a;
    r += __shfl_xor(r, 8);
    return r;  // lane id holds sum for q = id&7 (duplicated on id>=8)
}

// One block per batch element. 256 threads = 4 waves. State LDS-resident.
__global__ __launch_bounds__(256, 2)
void bottleneck_fusion_kernel(const float* __restrict__ l1,
                              const float* __restrict__ a1,
                              const float* __restrict__ v1,
                              const float* __restrict__ lat,
                              const float* __restrict__ psl,
                              const float* __restrict__ psa,
                              const float* __restrict__ psv,
                              float* __restrict__ out)
{
    __shared__ __align__(16) float st[NR * STRIDE];     // state rows l=0..15,a=16..31,v=32..47
    __shared__ __align__(16) float fz[NLAT * STRIDE];   // fused rows
    __shared__ __align__(16) float latl[NLAT * STRIDE]; // latents, pre-scaled by C^-0.5
    __shared__ __align__(16) float s1t[NR * NLAT];      // scores1^T [k][q] -> weights1^T
    __shared__ __align__(16) float s2t[NR * NLAT];      // scores2   [r][j] -> weights2

    const int t    = threadIdx.x;
    const int wave = t >> 6;
    const int lane = t & 63;
    const int cg   = lane & 15;  // 16-lane dot group: owns cols {cg*4+i + 64*h}
    const int rs   = lane >> 4;  // row-sub (4 rows per wave pass)
    const int b    = blockIdx.x;

    // ---- stage state rows (coalesced float4) + pre-scaled latents into LDS
    for (int idx = t; idx < NR * 64; idx += 256) {
        const int r = idx >> 6, c4 = idx & 63;
        const float* src = (r < 16) ? l1 : (r < 32) ? a1 : v1;
        const int row = r & 15;
        *(float4*)&st[r * STRIDE + c4 * 4] =
            *(const float4*)(src + ((size_t)b * SEQ + row) * CDIM + c4 * 4);
    }
    for (int idx = t; idx < NLAT * 64; idx += 256) {
        const int q = idx >> 6, c4 = idx & 63;
        float4 lv = *(const float4*)(lat + q * CDIM + c4 * 4);
        lv.x *= 0.0625f; lv.y *= 0.0625f; lv.z *= 0.0625f; lv.w *= 0.0625f;
        *(float4*)&latl[q * STRIDE + c4 * 4] = lv;
    }
    const float sc_l = psl[0], sc_a = psa[0], sc_v = psv[0];
    __syncthreads();

    for (int it = 0; it < 3; ++it) {
        // ===== P1a: s1t[k][q] = latl[q] . st[k]   (latl pre-scaled)
        {
            float latf[NLAT][16];
            #pragma unroll
            for (int q = 0; q < NLAT; ++q)
                #pragma unroll
                for (int h = 0; h < 4; ++h) {
                    const float4 lv = *(const float4*)&latl[q * STRIDE + h * 64 + cg * 4];
                    latf[q][h*4+0] = lv.x; latf[q][h*4+1] = lv.y;
                    latf[q][h*4+2] = lv.z; latf[q][h*4+3] = lv.w;
                }
            #pragma unroll
            for (int g = 0; g < 3; ++g) {
                const int r = wave * 12 + g * 4 + rs;
                float x[16];
                #pragma unroll
                for (int h = 0; h < 4; ++h) {
                    const float4 xv = *(const float4*)&st[r * STRIDE + h * 64 + cg * 4];
                    x[h*4+0] = xv.x; x[h*4+1] = xv.y; x[h*4+2] = xv.z; x[h*4+3] = xv.w;
                }
                float acc[NLAT];
                #pragma unroll
                for (int q = 0; q < NLAT; ++q) {
                    float s = 0.f;
                    #pragma unroll
                    for (int c = 0; c < 16; ++c) s = fmaf(x[c], latf[q][c], s);
                    acc[q] = s;
                }
                const float wv = reduce8x16(acc, cg);
                if (cg < NLAT) s1t[r * NLAT + cg] = wv;
            }
        }
        __syncthreads();

        // ===== softmax over 48 keys per latent q (half-wave each)
        {
            const int q = wave * 2 + (lane >> 5);
            const int j = lane & 31;
            const float va = s1t[j * NLAT + q];
            const float vb = (j < 16) ? s1t[(32 + j) * NLAT + q] : -1e30f;
            float m = fmaxf(va, vb);
            #pragma unroll
            for (int s = 1; s <= 16; s <<= 1) m = fmaxf(m, __shfl_xor(m, s));
            const float ea = __expf(va - m);
            const float eb = (j < 16) ? __expf(vb - m) : 0.f;
            float ssum = ea + eb;
            #pragma unroll
            for (int s = 1; s <= 16; s <<= 1) ssum += __shfl_xor(ssum, s);
            const float inv = 1.f / ssum;
            s1t[j * NLAT + q] = ea * inv;
            if (j < 16) s1t[(32 + j) * NLAT + q] = eb * inv;
        }
        __syncthreads();

        // ===== P1c: fz[q][c] = sum_k w1[k][q] * st[k][c]
        // Column-per-lane: thread t owns column c=t; weight reads are wave-broadcast.
        {
            float f[NLAT] = {0,0,0,0,0,0,0,0};
            #pragma unroll 4
            for (int k = 0; k < NR; ++k) {
                const float x = st[k * STRIDE + t];
                const float4 wa = *(const float4*)&s1t[k * NLAT];
                const float4 wb = *(const float4*)&s1t[k * NLAT + 4];
                f[0] = fmaf(wa.x, x, f[0]); f[1] = fmaf(wa.y, x, f[1]);
                f[2] = fmaf(wa.z, x, f[2]); f[3] = fmaf(wa.w, x, f[3]);
                f[4] = fmaf(wb.x, x, f[4]); f[5] = fmaf(wb.y, x, f[5]);
                f[6] = fmaf(wb.z, x, f[6]); f[7] = fmaf(wb.w, x, f[7]);
            }
            #pragma unroll
            for (int q = 0; q < NLAT; ++q) fz[q * STRIDE + t] = f[q];
        }
        __syncthreads();

        // ===== P2a: s2t[r][j] = (st[r] . fz[j]) * C^-0.5
        // it==2: only l-row 15 feeds the output -> wave 1, pass 0 only.
        if (it < 2 || wave == 1) {
            float ff[NLAT][16];
            #pragma unroll
            for (int q = 0; q < NLAT; ++q)
                #pragma unroll
                for (int h = 0; h < 4; ++h) {
                    const float4 fv = *(const float4*)&fz[q * STRIDE + h * 64 + cg * 4];
                    ff[q][h*4+0] = fv.x; ff[q][h*4+1] = fv.y;
                    ff[q][h*4+2] = fv.z; ff[q][h*4+3] = fv.w;
                }
            #pragma unroll
            for (int g = 0; g < 3; ++g) {
                if (it == 2 && g != 0) continue;
                const int r = wave * 12 + g * 4 + rs;
                float x[16];
                #pragma unroll
                for (int h = 0; h < 4; ++h) {
                    const float4 xv = *(const float4*)&st[r * STRIDE + h * 64 + cg * 4];
                    x[h*4+0] = xv.x; x[h*4+1] = xv.y; x[h*4+2] = xv.z; x[h*4+3] = xv.w;
                }
                float acc[NLAT];
                #pragma unroll
                for (int q = 0; q < NLAT; ++q) {
                    float s = 0.f;
                    #pragma unroll
                    for (int c = 0; c < 16; ++c) s = fmaf(x[c], ff[q][c], s);
                    acc[q] = s * 0.0625f;
                }
                const float wv = reduce8x16(acc, cg);
                if (cg < NLAT) s2t[r * NLAT + cg] = wv;
            }
        }
        __syncthreads();

        // ===== softmax over 8 fused keys per state row
        {
            for (int r = (t >> 3); r < NR; r += 32) {
                const float v = s2t[r * NLAT + (t & 7)];
                float m = v;
                #pragma unroll
                for (int s = 1; s <= 4; s <<= 1) m = fmaxf(m, __shfl_xor(m, s));
                const float e = __expf(v - m);
                float ssum = e;
                #pragma unroll
                for (int s = 1; s <= 4; s <<= 1) ssum += __shfl_xor(ssum, s);
                s2t[r * NLAT + (t & 7)] = e / ssum;
            }
        }
        __syncthreads();

        // ===== P2b: st[r] += scale_s * (w2[r] @ fz)
        if (it < 2 || wave == 1) {
            float f2[NLAT][4];
            #pragma unroll
            for (int j = 0; j < NLAT; ++j) {
                const float4 fv = *(const float4*)&fz[j * STRIDE + lane * 4];
                f2[j][0] = fv.x; f2[j][1] = fv.y; f2[j][2] = fv.z; f2[j][3] = fv.w;
            }
            for (int rr = 0; rr < 12; ++rr) {
                const int r = wave * 12 + rr;
                if (it == 2 && r != 15) continue;
                float w[NLAT];
                #pragma unroll
                for (int j = 0; j < NLAT; ++j) w[j] = s2t[r * NLAT + j];
                float4 xv = *(float4*)&st[r * STRIDE + lane * 4];
                float o0 = 0, o1 = 0, o2 = 0, o3 = 0;
                #pragma unroll
                for (int j = 0; j < NLAT; ++j) {
                    o0 = fmaf(w[j], f2[j][0], o0);
                    o1 = fmaf(w[j], f2[j][1], o1);
                    o2 = fmaf(w[j], f2[j][2], o2);
                    o3 = fmaf(w[j], f2[j][3], o3);
                }
                const float sc = (r < 16) ? sc_l : (r < 32) ? sc_a : sc_v;
                xv.x = fmaf(sc, o0, xv.x); xv.y = fmaf(sc, o1, xv.y);
                xv.z = fmaf(sc, o2, xv.z); xv.w = fmaf(sc, o3, xv.w);
                *(float4*)&st[r * STRIDE + lane * 4] = xv;
            }
        }
        __syncthreads();
    }

    // output = l1 row 15 (last time step)
    if (t < 64) {
        *(float4*)(out + (size_t)b * CDIM + t * 4) = *(const float4*)&st[15 * STRIDE + t * 4];
    }
}

} // namespace

extern "C" void kernel_launch(void* const* d_in, const int* in_sizes, int n_in,
                              void* d_out, int out_size, void* d_ws, size_t ws_size,
                              hipStream_t stream) {
    const float* l1  = (const float*)d_in[0];
    const float* a1  = (const float*)d_in[1];
    const float* v1  = (const float*)d_in[2];
    const float* lat = (const float*)d_in[3];
    const float* psl = (const float*)d_in[4];
    const float* psa = (const float*)d_in[5];
    const float* psv = (const float*)d_in[6];
    float* out = (float*)d_out;

    const int B = in_sizes[0] / (SEQ * CDIM);  // 8192
    dim3 grid(B), block(256);
    hipLaunchKernelGGL(bottleneck_fusion_kernel, grid, block, 0, stream,
                       l1, a1, v1, lat, psl, psa, psv, out);
}